// Round 2
// 214.158 us; speedup vs baseline: 1.0092x; 1.0092x over previous
//
#include <hip/hip_runtime.h>
#include <hip/hip_bf16.h>
#include <math.h>

// Problem constants (B,C,D,H,W) = (2,64,32,64,96), qk=32
constexpr int Cc = 64, Dd = 32, Hh = 64, Ww = 96, QKd = 32;
constexpr int CSTRIDE = Dd * Hh * Ww;   // 196608
constexpr int BDIM = 256;               // 4 waves

// ln(10000)/32 and ln(10000)/64
#define FREQ_QK 0.28782313662425574f
#define FREQ_V  0.14391156831212787f
#define LOG2E   1.44269504088896340736f

typedef __bf16 bf16_t;
typedef bf16_t bf16x8 __attribute__((ext_vector_type(8)));
typedef bf16_t bf16x4 __attribute__((ext_vector_type(4)));
typedef float  floatx4 __attribute__((ext_vector_type(4)));

// LDS layout (bf16 elements), 39424 B total -> 4 blocks/CU (was 48640 -> 3).
//  Xs [96 w][72]      : X^T bf16 (B-operand for projections)    6912 el  [0,6912)
//  Qs [96 w][32 swz]  : Q^T, XOR-swizzled (el ^= (w&7)<<3)      3072 el  [6912,9984)
//  Ks [96 w][32 swz]  : K^T, XOR-swizzled                       3072 el  [9984,13056)
//  Vs [64 c][104]     : V   (A-operand for PV)                  6656 el  [13056,19712)
//  Ps [96 i][104]     : P   (B-operand for PV)                  9984 el  [0,9984)  overlays Xs+Qs
// Ps overlays Qs, so ALL waves must pull their Q (and we also hoist K) fragments
// into registers, then barrier, before any P write. Ks/Vs are never overlaid.
// Swizzled Qs/Ks frag reads: lanes l16 and l16+8 alias (2-way = free, m136);
// all other lanes hit distinct 16B bank groups.
constexpr int XS_STRIDE = 72;
constexpr int QS_STRIDE = 32;
constexpr int VS_STRIDE = 104;
constexpr int PS_STRIDE = 104;
constexpr int OFF_QS = 6912;
constexpr int OFF_KS = 6912 + 3072;          // 9984
constexpr int OFF_VS = OFF_KS + 3072;        // 13056
constexpr int SMEM_ELEMS = OFF_VS + 6656;    // 19712 el = 39424 B

__global__ __launch_bounds__(BDIM, 4)
void row_attn_mfma(const float* __restrict__ x,
                   const float* __restrict__ Wq, const float* __restrict__ bq,
                   const float* __restrict__ Wk, const float* __restrict__ bk,
                   const float* __restrict__ Wv, const float* __restrict__ bv,
                   const float* __restrict__ gamma,
                   float* __restrict__ y)
{
    __shared__ __align__(16) bf16_t smem[SMEM_ELEMS];
    bf16_t* Xs = smem;            // dead after projections
    bf16_t* Ps = smem;            // written in S stage (after Q/K frags are in regs)
    bf16_t* Qs = smem + OFF_QS;
    bf16_t* Ks = smem + OFF_KS;
    bf16_t* Vs = smem + OFF_VS;

    const int t    = threadIdx.x;
    const int lane = t & 63;
    const int wid  = t >> 6;       // wave id 0..3
    const int l16  = lane & 15;
    const int quad = lane >> 4;    // 0..3

    const int bid = blockIdx.x;
    const int b   = bid / (Dd * Hh);
    const int rem = bid % (Dd * Hh);
    const int d   = rem / Hh;
    const int h   = rem % Hh;
    const int base0 = b * (Cc * CSTRIDE) + d * (Hh * Ww) + h * Ww;

    // ---- stage X^T into LDS as bf16: Xs[w][c] ----
#pragma unroll
    for (int k = 0; k < 12; ++k) {
        int idx = t + k * BDIM;          // 0..3071
        int w  = idx % Ww;
        int c  = (idx / Ww) * 2;         // even c
        float v0 = x[base0 + c * CSTRIDE + w];
        float v1 = x[base0 + (c + 1) * CSTRIDE + w];
        unsigned short u0 = __builtin_bit_cast(unsigned short, (bf16_t)v0);
        unsigned short u1 = __builtin_bit_cast(unsigned short, (bf16_t)v1);
        *(unsigned int*)(&Xs[w * XS_STRIDE + c]) = (unsigned)u0 | ((unsigned)u1 << 16);
    }

    // ---- per-wave weight A-fragments (from global fp32, L1/L2-hot) ----
    const float* Wmat = (wid == 0) ? Wq : (wid == 1) ? Wk : Wv;
    const float* bias = (wid == 0) ? bq : (wid == 1) ? bk : bv;
    const float freqc = (wid < 2) ? FREQ_QK : FREQ_V;
    const int   mbase = (wid == 3) ? 32 : 0;

    bf16x8 wfrag[2][2];
#pragma unroll
    for (int mt = 0; mt < 2; ++mt)
#pragma unroll
        for (int kt = 0; kt < 2; ++kt) {
            const float* p = Wmat + (mbase + mt * 16 + l16) * 64 + kt * 32 + quad * 8;
            float4 lo = *(const float4*)p;
            float4 hi = *(const float4*)(p + 4);
            bf16x8 f;
            f[0] = (bf16_t)lo.x; f[1] = (bf16_t)lo.y; f[2] = (bf16_t)lo.z; f[3] = (bf16_t)lo.w;
            f[4] = (bf16_t)hi.x; f[5] = (bf16_t)hi.y; f[6] = (bf16_t)hi.z; f[7] = (bf16_t)hi.w;
            wfrag[mt][kt] = f;
        }
    float biasv[2][4], freq2[2][2];
#pragma unroll
    for (int mt = 0; mt < 2; ++mt) {
#pragma unroll
        for (int r = 0; r < 4; ++r)
            biasv[mt][r] = bias[mbase + mt * 16 + quad * 4 + r];
#pragma unroll
        for (int p2 = 0; p2 < 2; ++p2)
            freq2[mt][p2] = __expf(-(float)(mbase + mt * 16 + quad * 4 + 2 * p2) * freqc);
    }
    __syncthreads();

    // ---- projections: wave0 -> Qs (pre-scaled by log2e), wave1 -> Ks, waves2/3 -> Vs ----
    bf16_t* dstQK = (wid == 0) ? Qs : Ks;
#pragma unroll
    for (int nt = 0; nt < 6; ++nt) {
        bf16x8 bfr[2];
#pragma unroll
        for (int kt = 0; kt < 2; ++kt)
            bfr[kt] = *(const bf16x8*)(&Xs[(nt * 16 + l16) * XS_STRIDE + kt * 32 + quad * 8]);
#pragma unroll
        for (int mt = 0; mt < 2; ++mt) {
            floatx4 acc = {0.f, 0.f, 0.f, 0.f};
            acc = __builtin_amdgcn_mfma_f32_16x16x32_bf16(wfrag[mt][0], bfr[0], acc, 0, 0, 0);
            acc = __builtin_amdgcn_mfma_f32_16x16x32_bf16(wfrag[mt][1], bfr[1], acc, 0, 0, 0);
            float wv = (float)(nt * 16 + l16);
            float out[4];
#pragma unroll
            for (int p2 = 0; p2 < 2; ++p2) {
                float sn, cs;
                __sincosf(wv * freq2[mt][p2], &sn, &cs);
                out[2 * p2]     = acc[2 * p2]     + biasv[mt][2 * p2]     + sn;
                out[2 * p2 + 1] = acc[2 * p2 + 1] + biasv[mt][2 * p2 + 1] + cs;
            }
            if (wid < 2) {
                // fold log2e into Q so softmax can use native exp2
                if (wid == 0) {
#pragma unroll
                    for (int r = 0; r < 4; ++r) out[r] *= LOG2E;
                }
                bf16x4 pk;
                pk[0] = (bf16_t)out[0]; pk[1] = (bf16_t)out[1];
                pk[2] = (bf16_t)out[2]; pk[3] = (bf16_t)out[3];
                const int w  = nt * 16 + l16;
                const int el = (w * QS_STRIDE + mt * 16 + quad * 4) ^ ((w & 7) << 3);
                *(bf16x4*)(&dstQK[el]) = pk;
            } else {
#pragma unroll
                for (int r = 0; r < 4; ++r)
                    Vs[(mbase + mt * 16 + quad * 4 + r) * VS_STRIDE + nt * 16 + l16] = (bf16_t)out[r];
            }
        }
    }
    __syncthreads();

    // ---- preload Q (B-operand) and K (A-operand) fragments into registers ----
    // i-tiles: wave0 {0,1}, wave1 {2,3}, wave2 {4}, wave3 {5}
    const int it0 = (wid < 2) ? wid * 2 : wid + 2;
    const int itc = (wid < 2) ? 2 : 1;
    bf16x8 qfr[2];
#pragma unroll
    for (int ii = 0; ii < 2; ++ii) {
        const int it = it0 + ((itc == 2) ? ii : 0);
        const int w  = it * 16 + l16;
        qfr[ii] = *(const bf16x8*)(&Qs[(w * QS_STRIDE + quad * 8) ^ ((w & 7) << 3)]);
    }
    bf16x8 kfr[6];
#pragma unroll
    for (int jt = 0; jt < 6; ++jt) {
        const int w = jt * 16 + l16;
        kfr[jt] = *(const bf16x8*)(&Ks[(w * QS_STRIDE + quad * 8) ^ ((w & 7) << 3)]);
    }
    __syncthreads();   // all Q reads done before any P write (Ps overlays Qs)

    // ---- S^T = K^T Q : sacc[jt][r] = S[i=it*16+l16][j=jt*16+quad*4+r] ----
    // Row-i softmax reduction: 24 in-register values per lane, then combine
    // across the 4 quads sharing l16 via xor16 + xor32 (2 shuffles, was 8).
    for (int ii = 0; ii < itc; ++ii) {
        const int it = it0 + ii;
        floatx4 sacc[6];
#pragma unroll
        for (int jt = 0; jt < 6; ++jt) {
            floatx4 z = {0.f, 0.f, 0.f, 0.f};
            sacc[jt] = __builtin_amdgcn_mfma_f32_16x16x32_bf16(kfr[jt], qfr[ii], z, 0, 0, 0);
        }
        float mr[6];
#pragma unroll
        for (int jt = 0; jt < 6; ++jt)
            mr[jt] = fmaxf(fmaxf(sacc[jt][0], sacc[jt][1]), fmaxf(sacc[jt][2], sacc[jt][3]));
        float m = fmaxf(fmaxf(fmaxf(mr[0], mr[1]), fmaxf(mr[2], mr[3])), fmaxf(mr[4], mr[5]));
        m = fmaxf(m, __shfl_xor(m, 16));
        m = fmaxf(m, __shfl_xor(m, 32));
        float sum = 0.f;
#pragma unroll
        for (int jt = 0; jt < 6; ++jt) {
#pragma unroll
            for (int r = 0; r < 4; ++r) {
                float e = exp2f(sacc[jt][r] - m);   // Q pre-scaled by log2e
                sacc[jt][r] = e;
                sum += e;
            }
        }
        sum += __shfl_xor(sum, 16);
        sum += __shfl_xor(sum, 32);
        const float inv = __builtin_amdgcn_rcpf(sum);
        const int row = it * 16 + l16;
#pragma unroll
        for (int jt = 0; jt < 6; ++jt) {
            bf16x4 pk;
            pk[0] = (bf16_t)(sacc[jt][0] * inv);
            pk[1] = (bf16_t)(sacc[jt][1] * inv);
            pk[2] = (bf16_t)(sacc[jt][2] * inv);
            pk[3] = (bf16_t)(sacc[jt][3] * inv);
            // P[i][j]: 4 consecutive j (quad*4+r) -> one b64 write
            *(bf16x4*)(&Ps[row * PS_STRIDE + jt * 16 + quad * 4]) = pk;
        }
    }
    __syncthreads();

    // ---- O = V @ P^T : wave handles c-tile = wid; fused gamma*o + x writeout ----
    const float g = gamma[0];
    const int ct = wid;
    bf16x8 vfr[3];
#pragma unroll
    for (int ks = 0; ks < 3; ++ks)
        vfr[ks] = *(const bf16x8*)(&Vs[(ct * 16 + l16) * VS_STRIDE + ks * 32 + quad * 8]);
#pragma unroll
    for (int it = 0; it < 6; ++it) {
        floatx4 acc = {0.f, 0.f, 0.f, 0.f};
#pragma unroll
        for (int ks = 0; ks < 3; ++ks) {
            bf16x8 bfr = *(const bf16x8*)(&Ps[(it * 16 + l16) * PS_STRIDE + ks * 32 + quad * 8]);
            acc = __builtin_amdgcn_mfma_f32_16x16x32_bf16(vfr[ks], bfr, acc, 0, 0, 0);
        }
#pragma unroll
        for (int r = 0; r < 4; ++r) {
            int c  = ct * 16 + quad * 4 + r;
            int gi = base0 + c * CSTRIDE + it * 16 + l16;
            y[gi] = fmaf(g, acc[r], x[gi]);   // exact fp32 residual
        }
    }
}

extern "C" void kernel_launch(void* const* d_in, const int* in_sizes, int n_in,
                              void* d_out, int out_size, void* d_ws, size_t ws_size,
                              hipStream_t stream) {
    const float* x     = (const float*)d_in[0];
    const float* Wq    = (const float*)d_in[1];
    const float* bq    = (const float*)d_in[2];
    const float* Wk    = (const float*)d_in[3];
    const float* bk    = (const float*)d_in[4];
    const float* Wv    = (const float*)d_in[5];
    const float* bv    = (const float*)d_in[6];
    const float* gamma = (const float*)d_in[7];
    float* y = (float*)d_out;

    dim3 grid(2 * 32 * 64);   // one block per (b,d,h)
    row_attn_mfma<<<grid, BDIM, 0, stream>>>(x, Wq, bq, Wk, bk, Wv, bv, gamma, y);
}